// Round 5
// baseline (744.769 us; speedup 1.0000x reference)
//
#include <hip/hip_runtime.h>
#include <math.h>

#define B_ 64
#define P_ 8732
#define M_ 16
#define C_ 81
#define THRESH 0.5f
#define EPS_ 1e-7f

#define CE_TILE 64
#define NBLK_CE ((B_ * P_) / CE_TILE)    // 8732

// ---------------------------------------------------------------------------
// Kernel 1: per-batch prior assignment (faithful: j_idx filtered-index bug +
// last-write-wins). Also zeroes the fused kernel's sync counters.
// ---------------------------------------------------------------------------
__global__ __launch_bounds__(1024) void assign_kernel(
    const float* __restrict__ boxes,
    const int*   __restrict__ labels,
    const float* __restrict__ priors,
    int*         __restrict__ true_classes,
    int*         __restrict__ n_pos,
    int*         __restrict__ cnt,      // [B] row-completion counters
    int*         __restrict__ done)     // [1] batch-completion counter
{
    const int b = blockIdx.x;
    const int tid = threadIdx.x;
    const int lane = tid & 63;
    const int wv = tid >> 6;

    __shared__ float s_ovl[P_];
    __shared__ unsigned char s_obj[P_];
    __shared__ float s_bx[M_][4];
    __shared__ float s_barea[M_];
    __shared__ int   s_lab[M_];
    __shared__ float s_wv[M_][16];
    __shared__ int   s_wp[M_][16];
    __shared__ float s_ovl_obj[M_];
    __shared__ int   s_prior_obj[M_];
    __shared__ int   s_cnt[16];

    if (tid == 0) {
        atomicExch(&cnt[b], 0);          // coherent-point zeroing
        if (b == 0) atomicExch(done, 0);
    }

    if (tid < M_*4) ((float*)s_bx)[tid] = boxes[b*M_*4 + tid];
    if (tid < M_)   s_lab[tid] = labels[b*M_ + tid];
    __syncthreads();
    if (tid < M_)
        s_barea[tid] = (s_bx[tid][2]-s_bx[tid][0])*(s_bx[tid][3]-s_bx[tid][1]);
    __syncthreads();

    float bestv[M_]; int bestp[M_];
    #pragma unroll
    for (int m = 0; m < M_; ++m) { bestv[m] = -1.0f; bestp[m] = 0x7fffffff; }

    for (int p = tid; p < P_; p += 1024) {
        float4 pc = ((const float4*)priors)[p];
        float px1 = pc.x - pc.z*0.5f, py1 = pc.y - pc.w*0.5f;
        float px2 = pc.x + pc.z*0.5f, py2 = pc.y + pc.w*0.5f;
        float parea = (px2-px1)*(py2-py1);
        float bv = -1.0f; int bm = 0;
        #pragma unroll
        for (int m = 0; m < M_; ++m) {
            float ix1 = fmaxf(s_bx[m][0], px1);
            float iy1 = fmaxf(s_bx[m][1], py1);
            float ix2 = fminf(s_bx[m][2], px2);
            float iy2 = fminf(s_bx[m][3], py2);
            float iw = fmaxf(ix2-ix1, 0.0f);
            float ih = fmaxf(iy2-iy1, 0.0f);
            float inter = iw*ih;
            float iou = inter / (s_barea[m] + parea - inter);
            if (iou > bv) { bv = iou; bm = m; }
            if (iou > bestv[m]) { bestv[m] = iou; bestp[m] = p; }
        }
        s_ovl[p] = bv;
        s_obj[p] = (unsigned char)bm;
    }

    #pragma unroll
    for (int m = 0; m < M_; ++m) {
        float v = bestv[m]; int p = bestp[m];
        #pragma unroll
        for (int o = 32; o; o >>= 1) {
            float v2 = __shfl_xor(v, o);
            int   p2 = __shfl_xor(p, o);
            if (v2 > v || (v2 == v && p2 < p)) { v = v2; p = p2; }
        }
        if (lane == 0) { s_wv[m][wv] = v; s_wp[m][wv] = p; }
    }
    __syncthreads();

    if (tid < M_) {
        float v = s_wv[tid][0]; int p = s_wp[tid][0];
        #pragma unroll
        for (int w = 1; w < 16; ++w) {
            float v2 = s_wv[tid][w]; int p2 = s_wp[tid][w];
            if (v2 > v || (v2 == v && p2 < p)) { v = v2; p = p2; }
        }
        s_ovl_obj[tid] = v; s_prior_obj[tid] = p;
    }
    __syncthreads();

    if (tid == 0) {
        int c = 0;
        for (int m = 0; m < M_; ++m) {
            if (s_ovl_obj[m] > 0.0f) {
                int p = s_prior_obj[m];
                s_ovl[p] = 1.0f;
                s_obj[p] = (unsigned char)c;   // faithful filtered index
                c++;
            }
        }
    }
    __syncthreads();

    int cpos = 0;
    for (int p = tid; p < P_; p += 1024) {
        int tc = 0;
        if (!(s_ovl[p] < THRESH)) tc = s_lab[s_obj[p]];
        true_classes[(size_t)b*P_ + p] = tc;
        cpos += (tc > 0);
    }
    #pragma unroll
    for (int o = 32; o; o >>= 1) cpos += __shfl_xor(cpos, o);
    if (lane == 0) s_cnt[wv] = cpos;
    __syncthreads();
    if (tid == 0) {
        int t = 0;
        #pragma unroll
        for (int w = 0; w < 16; ++w) t += s_cnt[w];
        n_pos[b] = t;
    }
}

// ---------------------------------------------------------------------------
// Kernel 2 (fused): CE + DIoU tile -> per-batch topk (last block per batch)
// -> final scalar (last batch overall). 256 threads, 21 KB LDS, 7 blocks/CU.
// ---------------------------------------------------------------------------
struct SA { float s[CE_TILE*C_]; int tc[CE_TILE]; float cf[CE_TILE]; float red[4][2]; };
struct SB { int hist[4][256]; int cg[257]; float f[4]; int t[4]; int sel; };
union SMem { SA a; SB b; };

__device__ void do_topk(int bx, const float* __restrict__ conf_neg,
                        const int* __restrict__ n_pos,
                        const float* __restrict__ blk_pos,
                        const float* __restrict__ blk_loc,
                        float* __restrict__ hard,
                        float* __restrict__ partial_p,
                        float* __restrict__ partial_l,
                        SMem& sm, int tid, int lane, int wv)
{
    // slice sums of blk partials (tiles whose first row is in batch bx)
    {
        const int s0 = (bx * P_ + CE_TILE - 1) / CE_TILE;
        const int s1 = ((bx + 1) * P_ + CE_TILE - 1) / CE_TILE;
        float sp = 0.f, sl = 0.f;
        for (int t = s0 + tid; t < s1; t += 256) { sp += blk_pos[t]; sl += blk_loc[t]; }
        #pragma unroll
        for (int o = 32; o; o >>= 1) { sp += __shfl_xor(sp, o); sl += __shfl_xor(sl, o); }
        if (lane == 0) { sm.b.f[wv] = sp; sm.b.cg[wv] = __float_as_int(sl); }
        __syncthreads();
        if (tid == 0) {
            partial_p[bx] = sm.b.f[0] + sm.b.f[1] + sm.b.f[2] + sm.b.f[3];
            partial_l[bx] = __int_as_float(sm.b.cg[0]) + __int_as_float(sm.b.cg[1])
                          + __int_as_float(sm.b.cg[2]) + __int_as_float(sm.b.cg[3]);
        }
        __syncthreads();
    }

    int k = 3 * n_pos[bx];
    if (k <= 0) { if (tid == 0) hard[bx] = 0.f; return; }   // block-uniform
    if (k > P_) k = P_;

    const float* cv = conf_neg + (size_t)bx * P_;
    const unsigned masks[4]  = {0u, 0xFF800000u, 0xFFFF8000u, 0xFFFFFF80u};
    const int      shifts[4] = {23, 15, 7, 0};
    unsigned prefix = 0u;
    int k_rem = k;

    for (int rd = 0; rd < 4; ++rd) {
        const unsigned hm = masks[rd];
        const int sh = shifts[rd];

        #pragma unroll
        for (int i = 0; i < 4; ++i) ((int*)sm.b.hist)[tid + 256*i] = 0;
        __syncthreads();

        for (int i = tid; i < P_; i += 256) {
            unsigned u = __float_as_uint(cv[i]);
            if ((u & hm) == prefix)
                atomicAdd(&sm.b.hist[wv][(u >> sh) & 0xFF], 1);
        }
        __syncthreads();

        if (tid < 64) {                       // wave 0: merge + suffix scan
            int carry = 0;
            for (int c = 3; c >= 0; --c) {
                int bin = c * 64 + lane;
                int tot = sm.b.hist[0][bin] + sm.b.hist[1][bin]
                        + sm.b.hist[2][bin] + sm.b.hist[3][bin];
                #pragma unroll
                for (int o = 1; o < 64; o <<= 1) {
                    int v = __shfl_down(tot, o);
                    if (lane + o < 64) tot += v;
                }
                int cg = tot + carry;
                sm.b.cg[bin] = cg;
                carry = __shfl(cg, 0);
            }
            if (lane == 0) sm.b.cg[256] = 0;
        }
        __syncthreads();

        if (sm.b.cg[tid] >= k_rem && sm.b.cg[tid + 1] < k_rem) sm.b.sel = tid;
        __syncthreads();

        const int bsel = sm.b.sel;
        k_rem -= sm.b.cg[bsel + 1];
        prefix |= (unsigned)bsel << sh;
        __syncthreads();
    }

    const float tval = __uint_as_float(prefix);
    float sum = 0.f; int cgt = 0;
    for (int i = tid; i < P_; i += 256) {
        float v = cv[i];
        if (v > tval) { sum += v; cgt++; }
    }
    #pragma unroll
    for (int o = 32; o; o >>= 1) { sum += __shfl_xor(sum, o); cgt += __shfl_xor(cgt, o); }
    if (lane == 0) { sm.b.f[wv] = sum; sm.b.t[wv] = cgt; }
    __syncthreads();
    if (tid == 0) {
        float s = sm.b.f[0] + sm.b.f[1] + sm.b.f[2] + sm.b.f[3];
        int   c = sm.b.t[0] + sm.b.t[1] + sm.b.t[2] + sm.b.t[3];
        hard[bx] = s + (float)(k - c) * tval;
    }
    __syncthreads();
}

__global__ __launch_bounds__(256) void fused_kernel(
    const float* __restrict__ scores,
    const float* __restrict__ locs,
    const int*   __restrict__ tcls,
    const int*   __restrict__ n_pos,
    float*       __restrict__ conf_neg,
    float*       __restrict__ blk_pos,
    float*       __restrict__ blk_loc,
    float*       __restrict__ hard,
    float*       __restrict__ partial_p,
    float*       __restrict__ partial_l,
    int*         __restrict__ cnt,
    int*         __restrict__ done,
    float*       __restrict__ out)
{
    __shared__ SMem sm;
    __shared__ int s_todo[2];
    __shared__ int s_final;

    const int tid  = threadIdx.x;
    const int tile = blockIdx.x;
    const int lane = tid & 63;
    const int wv   = tid >> 6;

    if (tid == 0) { s_todo[0] = -1; s_todo[1] = -1; s_final = 0; }

    // ---- Phase A: CE + DIoU for 64 rows ----
    {
        const float4* g4 = (const float4*)(scores + (size_t)tile * CE_TILE * C_);
        float4* s4 = (float4*)sm.a.s;
        #pragma unroll
        for (int k = 0; k < 5; ++k) s4[tid + 256*k] = g4[tid + 256*k];
        if (tid < 16) s4[tid + 1280] = g4[tid + 1280];
        if (tid < CE_TILE) sm.a.tc[tid] = tcls[tile * CE_TILE + tid];
    }
    __syncthreads();

    const int q    = tid & 3;
    const int lrow = tid >> 2;
    const float* row = sm.a.s + lrow * C_;

    float x[21];
    #pragma unroll
    for (int k = 0; k < 21; ++k) {
        const int idx = q + 4*k;
        x[k] = (idx < C_) ? row[idx] : -INFINITY;
    }
    float mx = x[0];
    #pragma unroll
    for (int k = 1; k < 21; ++k) mx = fmaxf(mx, x[k]);
    mx = fmaxf(mx, __shfl_xor(mx, 1));
    mx = fmaxf(mx, __shfl_xor(mx, 2));
    float e = 0.f;
    #pragma unroll
    for (int k = 0; k < 21; ++k) e += __expf(x[k] - mx);
    e += __shfl_xor(e, 1);
    e += __shfl_xor(e, 2);

    float p_acc = 0.f, l_acc = 0.f;
    if (q == 0) {
        const int r = tile * CE_TILE + lrow;
        const int t = sm.a.tc[lrow];
        float conf = mx + __logf(e) - row[t];
        if (t > 0) {
            sm.a.cf[lrow] = 0.f;
            p_acc = conf;
            float4 bx = ((const float4*)locs)[r];
            float w = bx.z - bx.x, h = bx.w - bx.y;
            float iw = fmaxf(w, 0.f), ih = fmaxf(h, 0.f);
            float inter = iw * ih;
            float area  = w * h;
            float iou   = inter / (area + area - inter + EPS_);
            float diou  = fminf(fmaxf(iou, -1.f), 1.f);
            l_acc = 1.f - diou;
        } else {
            sm.a.cf[lrow] = fmaxf(conf, 0.f);
        }
    }
    #pragma unroll
    for (int o = 32; o; o >>= 1) {
        p_acc += __shfl_xor(p_acc, o);
        l_acc += __shfl_xor(l_acc, o);
    }
    if (lane == 0) { sm.a.red[wv][0] = p_acc; sm.a.red[wv][1] = l_acc; }
    __syncthreads();

    if (wv == 0) conf_neg[tile * CE_TILE + lane] = sm.a.cf[lane];
    if (tid == 0) {
        blk_pos[tile] = sm.a.red[0][0] + sm.a.red[1][0] + sm.a.red[2][0] + sm.a.red[3][0];
        blk_loc[tile] = sm.a.red[0][1] + sm.a.red[1][1] + sm.a.red[2][1] + sm.a.red[3][1];
    }
    __syncthreads();   // barrier drains all vmem stores of the block

    // ---- Publish rows; last block per batch proceeds to topk ----
    if (tid == 0) {
        const int r0 = tile * CE_TILE;
        const int b0 = r0 / P_;
        const int end0 = (b0 + 1) * P_;
        const int n0 = min(CE_TILE, end0 - r0);
        const int n1 = CE_TILE - n0;
        __threadfence();                       // release conf_neg/blk writes
        int nw = 0;
        if (atomicAdd(&cnt[b0], n0) + n0 == P_) s_todo[nw++] = b0;
        if (n1 > 0) {
            if (atomicAdd(&cnt[b0 + 1], n1) + n1 == P_) s_todo[nw++] = b0 + 1;
        }
        if (nw) __threadfence();               // acquire others' writes
    }
    __syncthreads();

    int ncomp = 0;
    #pragma unroll
    for (int i = 0; i < 2; ++i) {
        const int bx = s_todo[i];
        if (bx >= 0) {
            do_topk(bx, conf_neg, n_pos, blk_pos, blk_loc,
                    hard, partial_p, partial_l, sm, tid, lane, wv);
            ncomp++;
        }
    }

    // ---- Last batch overall: final scalar ----
    if (ncomp) {
        if (tid == 0) {
            __threadfence();                   // release hard/partials
            if (atomicAdd(done, ncomp) + ncomp == B_) {
                __threadfence();               // acquire all batches
                s_final = 1;
            }
        }
        __syncthreads();
        if (s_final && tid < 64) {
            double h = hard[tid], pp = partial_p[tid], pl = partial_l[tid];
            double np = (double)n_pos[tid];
            #pragma unroll
            for (int o = 32; o; o >>= 1) {
                h  += __shfl_xor(h, o);  pp += __shfl_xor(pp, o);
                pl += __shfl_xor(pl, o); np += __shfl_xor(np, o);
            }
            if (tid == 0) {
                double conf_loss = (h + pp) / np;
                double loc_loss  = pl / fmax(np, 1.0);
                out[0] = (float)(conf_loss + loc_loss);
            }
        }
    }
}

extern "C" void kernel_launch(void* const* d_in, const int* in_sizes, int n_in,
                              void* d_out, int out_size, void* d_ws, size_t ws_size,
                              hipStream_t stream) {
    const float* predicted_locs   = (const float*)d_in[0];
    const float* predicted_scores = (const float*)d_in[1];
    const float* boxes            = (const float*)d_in[2];
    const int*   labels           = (const int*)d_in[3];
    const float* priors           = (const float*)d_in[4];
    float* out = (float*)d_out;

    char* ws = (char*)d_ws;
    size_t off = 0;
    int*    true_classes = (int*)(ws + off);   off += sizeof(int)   * (size_t)B_ * P_;
    float*  conf_neg     = (float*)(ws + off); off += sizeof(float) * (size_t)B_ * P_;
    float*  blk_pos      = (float*)(ws + off); off += sizeof(float) * NBLK_CE;
    float*  blk_loc      = (float*)(ws + off); off += sizeof(float) * NBLK_CE;
    int*    n_pos        = (int*)(ws + off);   off += sizeof(int)   * B_;
    float*  hard         = (float*)(ws + off); off += sizeof(float) * B_;
    float*  partial_p    = (float*)(ws + off); off += sizeof(float) * B_;
    float*  partial_l    = (float*)(ws + off); off += sizeof(float) * B_;
    int*    cnt          = (int*)(ws + off);   off += sizeof(int)   * B_;
    int*    done         = (int*)(ws + off);   off += sizeof(int)   * 1;

    assign_kernel<<<B_, 1024, 0, stream>>>(boxes, labels, priors,
                                           true_classes, n_pos, cnt, done);
    fused_kernel<<<NBLK_CE, 256, 0, stream>>>(predicted_scores, predicted_locs,
                                              true_classes, n_pos, conf_neg,
                                              blk_pos, blk_loc, hard,
                                              partial_p, partial_l, cnt, done, out);
}

// Round 6
// 359.784 us; speedup vs baseline: 2.0700x; 2.0700x over previous
//
#include <hip/hip_runtime.h>
#include <math.h>

#define B_ 64
#define P_ 8732
#define M_ 16
#define C_ 81
#define THRESH 0.5f
#define EPS_ 1e-7f

#define CE_TILE 64                       // rows per ce_loc block
#define NBLK_CE ((B_ * P_) / CE_TILE)    // 8732

// ---------------------------------------------------------------------------
// Kernel 1: per-batch prior assignment. 1024 threads/block, one block/batch.
// Faithful to reference incl. j_idx filtered-index bug + last-write-wins.
// Also zeroes the topk_final 'done' counter (visible via kernel ordering).
// ---------------------------------------------------------------------------
__global__ __launch_bounds__(1024) void assign_kernel(
    const float* __restrict__ boxes,    // [B,M,4] corner
    const int*   __restrict__ labels,   // [B,M]
    const float* __restrict__ priors,   // [P,4] cxcy
    int*         __restrict__ true_classes, // [B,P]
    int*         __restrict__ n_pos,    // [B]
    int*         __restrict__ done)     // [1]
{
    const int b = blockIdx.x;
    const int tid = threadIdx.x;
    const int lane = tid & 63;
    const int wv = tid >> 6;            // 16 waves

    __shared__ float s_ovl[P_];
    __shared__ unsigned char s_obj[P_];
    __shared__ float s_bx[M_][4];
    __shared__ float s_barea[M_];
    __shared__ int   s_lab[M_];
    __shared__ float s_wv[M_][16];
    __shared__ int   s_wp[M_][16];
    __shared__ float s_ovl_obj[M_];
    __shared__ int   s_prior_obj[M_];
    __shared__ int   s_cnt[16];

    if (b == 0 && tid == 0) atomicExch(done, 0);

    if (tid < M_*4) ((float*)s_bx)[tid] = boxes[b*M_*4 + tid];
    if (tid < M_)   s_lab[tid] = labels[b*M_ + tid];
    __syncthreads();
    if (tid < M_)
        s_barea[tid] = (s_bx[tid][2]-s_bx[tid][0])*(s_bx[tid][3]-s_bx[tid][1]);
    __syncthreads();

    float bestv[M_]; int bestp[M_];
    #pragma unroll
    for (int m = 0; m < M_; ++m) { bestv[m] = -1.0f; bestp[m] = 0x7fffffff; }

    for (int p = tid; p < P_; p += 1024) {
        float4 pc = ((const float4*)priors)[p];
        float px1 = pc.x - pc.z*0.5f, py1 = pc.y - pc.w*0.5f;
        float px2 = pc.x + pc.z*0.5f, py2 = pc.y + pc.w*0.5f;
        float parea = (px2-px1)*(py2-py1);
        float bv = -1.0f; int bm = 0;
        #pragma unroll
        for (int m = 0; m < M_; ++m) {
            float ix1 = fmaxf(s_bx[m][0], px1);
            float iy1 = fmaxf(s_bx[m][1], py1);
            float ix2 = fminf(s_bx[m][2], px2);
            float iy2 = fminf(s_bx[m][3], py2);
            float iw = fmaxf(ix2-ix1, 0.0f);
            float ih = fmaxf(iy2-iy1, 0.0f);
            float inter = iw*ih;
            float iou = inter / (s_barea[m] + parea - inter); // jaccard: no eps
            if (iou > bv) { bv = iou; bm = m; }               // first-max (m asc)
            if (iou > bestv[m]) { bestv[m] = iou; bestp[m] = p; } // first p wins
        }
        s_ovl[p] = bv;
        s_obj[p] = (unsigned char)bm;
    }

    #pragma unroll
    for (int m = 0; m < M_; ++m) {
        float v = bestv[m]; int p = bestp[m];
        #pragma unroll
        for (int o = 32; o; o >>= 1) {
            float v2 = __shfl_xor(v, o);
            int   p2 = __shfl_xor(p, o);
            if (v2 > v || (v2 == v && p2 < p)) { v = v2; p = p2; }
        }
        if (lane == 0) { s_wv[m][wv] = v; s_wp[m][wv] = p; }
    }
    __syncthreads();

    if (tid < M_) {
        float v = s_wv[tid][0]; int p = s_wp[tid][0];
        #pragma unroll
        for (int w = 1; w < 16; ++w) {
            float v2 = s_wv[tid][w]; int p2 = s_wp[tid][w];
            if (v2 > v || (v2 == v && p2 < p)) { v = v2; p = p2; }
        }
        s_ovl_obj[tid] = v; s_prior_obj[tid] = p;
    }
    __syncthreads();

    if (tid == 0) {
        int cnt = 0;
        for (int m = 0; m < M_; ++m) {
            if (s_ovl_obj[m] > 0.0f) {
                int p = s_prior_obj[m];
                s_ovl[p] = 1.0f;
                s_obj[p] = (unsigned char)cnt;  // faithful filtered index
                cnt++;
            }
        }
    }
    __syncthreads();

    int cpos = 0;
    for (int p = tid; p < P_; p += 1024) {
        int tc = 0;
        if (!(s_ovl[p] < THRESH)) tc = s_lab[s_obj[p]];
        true_classes[(size_t)b*P_ + p] = tc;
        cpos += (tc > 0);
    }
    #pragma unroll
    for (int o = 32; o; o >>= 1) cpos += __shfl_xor(cpos, o);
    if (lane == 0) s_cnt[wv] = cpos;
    __syncthreads();
    if (tid == 0) {
        int t = 0;
        #pragma unroll
        for (int w = 0; w < 16; ++w) t += s_cnt[w];
        n_pos[b] = t;
    }
}

// ---------------------------------------------------------------------------
// Kernel 2: CE over C=81 + positive-gated DIoU self-loss (proven R4 version).
// 256 threads stage a 64-row tile via contiguous float4, 4 lanes per row
// reduce from LDS, per-block partials to ws.
// ---------------------------------------------------------------------------
__global__ __launch_bounds__(256) void ce_loc_kernel(
    const float* __restrict__ scores,   // [B,P,C]
    const float* __restrict__ locs,     // [B,P,4]
    const int*   __restrict__ tcls,     // [B,P]
    float*       __restrict__ conf_neg, // [B,P]
    float*       __restrict__ blk_pos,  // [NBLK_CE]
    float*       __restrict__ blk_loc)  // [NBLK_CE]
{
    __shared__ float s[CE_TILE * C_];   // 20736 B
    __shared__ int   s_tc[CE_TILE];
    __shared__ float s_cf[CE_TILE];
    __shared__ float s_red[4][2];

    const int tid  = threadIdx.x;
    const int tile = blockIdx.x;
    const int lane = tid & 63;
    const int wv   = tid >> 6;

    {
        const float4* g4 = (const float4*)(scores + (size_t)tile * CE_TILE * C_);
        float4* s4 = (float4*)s;
        #pragma unroll
        for (int k = 0; k < 5; ++k) s4[tid + 256*k] = g4[tid + 256*k];
        if (tid < 16) s4[tid + 1280] = g4[tid + 1280];
        if (tid < CE_TILE) s_tc[tid] = tcls[tile * CE_TILE + tid];
    }
    __syncthreads();

    const int q    = tid & 3;
    const int lrow = tid >> 2;
    const float* row = s + lrow * C_;

    float x[21];
    #pragma unroll
    for (int k = 0; k < 21; ++k) {
        const int idx = q + 4*k;
        x[k] = (idx < C_) ? row[idx] : -INFINITY;
    }

    float mx = x[0];
    #pragma unroll
    for (int k = 1; k < 21; ++k) mx = fmaxf(mx, x[k]);
    mx = fmaxf(mx, __shfl_xor(mx, 1));
    mx = fmaxf(mx, __shfl_xor(mx, 2));

    float e = 0.f;
    #pragma unroll
    for (int k = 0; k < 21; ++k) e += __expf(x[k] - mx);
    e += __shfl_xor(e, 1);
    e += __shfl_xor(e, 2);

    float p_acc = 0.f, l_acc = 0.f;
    if (q == 0) {
        const int r = tile * CE_TILE + lrow;
        const int t = s_tc[lrow];
        float conf = mx + __logf(e) - row[t];   // -log_softmax[t]
        if (t > 0) {
            s_cf[lrow] = 0.f;
            p_acc = conf;
            float4 bx = ((const float4*)locs)[r];
            float w = bx.z - bx.x, h = bx.w - bx.y;
            float iw = fmaxf(w, 0.f), ih = fmaxf(h, 0.f);
            float inter = iw * ih;
            float area  = w * h;
            float iou   = inter / (area + area - inter + EPS_);
            float diou  = fminf(fmaxf(iou, -1.f), 1.f);
            l_acc = 1.f - diou;
        } else {
            s_cf[lrow] = fmaxf(conf, 0.f);      // order-monotonic float bits
        }
    }

    #pragma unroll
    for (int o = 32; o; o >>= 1) {
        p_acc += __shfl_xor(p_acc, o);
        l_acc += __shfl_xor(l_acc, o);
    }
    if (lane == 0) { s_red[wv][0] = p_acc; s_red[wv][1] = l_acc; }
    __syncthreads();

    if (wv == 0) conf_neg[tile * CE_TILE + lane] = s_cf[lane]; // coalesced
    if (tid == 0) {
        blk_pos[tile] = s_red[0][0] + s_red[1][0] + s_red[2][0] + s_red[3][0];
        blk_loc[tile] = s_red[0][1] + s_red[1][1] + s_red[2][1] + s_red[3][1];
    }
}

// ---------------------------------------------------------------------------
// Kernel 3 (merged topk+final): 64 blocks, one per batch. Histogram radix
// select (tie-exact), then last-done block (64 fences TOTAL — cheap, unlike
// R5's 8732) reduces partials + writes the scalar.
// ---------------------------------------------------------------------------
__global__ __launch_bounds__(1024) void topk_final_kernel(
    const float* __restrict__ conf_neg,
    const int*   __restrict__ n_pos,
    const float* __restrict__ blk_pos,
    const float* __restrict__ blk_loc,
    float*       __restrict__ hard,     // [B]
    int*         __restrict__ done,     // [1]
    float*       __restrict__ out)
{
    const int b = blockIdx.x;
    const int tid = threadIdx.x;
    const int lane = tid & 63;
    const int wv = tid >> 6;

    __shared__ float s_v[P_];           // 34928 B
    __shared__ int   s_hist[16][256];   // 16384 B
    __shared__ int   s_cg[257];
    __shared__ int   s_sel;
    __shared__ int   s_t[16];
    __shared__ float s_f[16];
    __shared__ int   s_last;
    __shared__ double sd[16][4];

    for (int i = tid; i < P_; i += 1024) s_v[i] = conf_neg[(size_t)b*P_ + i];
    int k = 3 * n_pos[b];
    if (k > P_) k = P_;
    __syncthreads();

    if (k > 0) {                         // block-uniform branch; barriers ok
        const unsigned masks[4]  = {0u, 0xFF800000u, 0xFFFF8000u, 0xFFFFFF80u};
        const int      shifts[4] = {23, 15, 7, 0};
        unsigned prefix = 0u;
        int k_rem = k;

        for (int rd = 0; rd < 4; ++rd) {
            const unsigned hm = masks[rd];
            const int sh = shifts[rd];

            ((int*)s_hist)[tid] = 0;
            ((int*)s_hist)[tid + 1024] = 0;
            ((int*)s_hist)[tid + 2048] = 0;
            ((int*)s_hist)[tid + 3072] = 0;
            __syncthreads();

            for (int i = tid; i < P_; i += 1024) {
                unsigned u = __float_as_uint(s_v[i]);
                if ((u & hm) == prefix)
                    atomicAdd(&s_hist[wv][(u >> sh) & 0xFF], 1);
            }
            __syncthreads();

            if (wv == 0) {               // merge 16 hists + suffix scan
                int carry = 0;
                for (int c = 3; c >= 0; --c) {
                    int bin = c * 64 + lane;
                    int tot = 0;
                    #pragma unroll
                    for (int w = 0; w < 16; ++w) tot += s_hist[w][bin];
                    #pragma unroll
                    for (int o = 1; o < 64; o <<= 1) {
                        int v = __shfl_down(tot, o);
                        if (lane + o < 64) tot += v;
                    }
                    int cg = tot + carry;
                    s_cg[bin] = cg;
                    carry = __shfl(cg, 0);
                }
                if (lane == 0) s_cg[256] = 0;
            }
            __syncthreads();

            if (tid < 256) {
                if (s_cg[tid] >= k_rem && s_cg[tid + 1] < k_rem) s_sel = tid;
            }
            __syncthreads();

            const int bsel = s_sel;
            k_rem -= s_cg[bsel + 1];
            prefix |= (unsigned)bsel << sh;
            __syncthreads();
        }

        const float tval = __uint_as_float(prefix);   // exact k-th largest
        float sum = 0.f; int cgt = 0;
        for (int i = tid; i < P_; i += 1024) {
            float v = s_v[i];
            if (v > tval) { sum += v; cgt++; }
        }
        #pragma unroll
        for (int o = 32; o; o >>= 1) { sum += __shfl_xor(sum, o); cgt += __shfl_xor(cgt, o); }
        if (lane == 0) { s_f[wv] = sum; s_t[wv] = cgt; }
        __syncthreads();
        if (tid == 0) {
            float s = 0.f; int c = 0;
            #pragma unroll
            for (int w = 0; w < 16; ++w) { s += s_f[w]; c += s_t[w]; }
            hard[b] = s + (float)(k - c) * tval;
        }
    } else {
        if (tid == 0) hard[b] = 0.f;
    }

    // publish + last-block election (64 device fences total — cheap)
    if (tid == 0) {
        __threadfence();                              // release hard[b]
        s_last = (atomicAdd(done, 1) == B_ - 1) ? 1 : 0;
    }
    __syncthreads();

    if (s_last) {
        if (tid == 0) __threadfence();                // acquire others' hard[]
        __syncthreads();

        double p = 0.0, l = 0.0;
        for (int i = tid; i < NBLK_CE; i += 1024) { p += blk_pos[i]; l += blk_loc[i]; }
        double h = 0.0, np = 0.0;
        if (tid < B_) { h = hard[tid]; np = (double)n_pos[tid]; }

        #pragma unroll
        for (int o = 32; o; o >>= 1) {
            p += __shfl_xor(p, o); l += __shfl_xor(l, o);
            h += __shfl_xor(h, o); np += __shfl_xor(np, o);
        }
        if (lane == 0) { sd[wv][0] = p; sd[wv][1] = l; sd[wv][2] = h; sd[wv][3] = np; }
        __syncthreads();
        if (tid == 0) {
            double tp = 0, tl = 0, th = 0, tn = 0;
            #pragma unroll
            for (int w = 0; w < 16; ++w) {
                tp += sd[w][0]; tl += sd[w][1]; th += sd[w][2]; tn += sd[w][3];
            }
            double conf_loss = (th + tp) / tn;
            double loc_loss  = tl / fmax(tn, 1.0);
            out[0] = (float)(conf_loss + loc_loss);
        }
    }
}

extern "C" void kernel_launch(void* const* d_in, const int* in_sizes, int n_in,
                              void* d_out, int out_size, void* d_ws, size_t ws_size,
                              hipStream_t stream) {
    const float* predicted_locs   = (const float*)d_in[0];
    const float* predicted_scores = (const float*)d_in[1];
    const float* boxes            = (const float*)d_in[2];
    const int*   labels           = (const int*)d_in[3];
    const float* priors           = (const float*)d_in[4];
    float* out = (float*)d_out;

    char* ws = (char*)d_ws;
    size_t off = 0;
    int*    true_classes = (int*)(ws + off);   off += sizeof(int)   * (size_t)B_ * P_;
    float*  conf_neg     = (float*)(ws + off); off += sizeof(float) * (size_t)B_ * P_;
    float*  blk_pos      = (float*)(ws + off); off += sizeof(float) * NBLK_CE;
    float*  blk_loc      = (float*)(ws + off); off += sizeof(float) * NBLK_CE;
    int*    n_pos        = (int*)(ws + off);   off += sizeof(int)   * B_;
    float*  hard         = (float*)(ws + off); off += sizeof(float) * B_;
    int*    done         = (int*)(ws + off);   off += sizeof(int)   * 1;

    assign_kernel<<<B_, 1024, 0, stream>>>(boxes, labels, priors,
                                           true_classes, n_pos, done);
    ce_loc_kernel<<<NBLK_CE, 256, 0, stream>>>(predicted_scores, predicted_locs,
                                               true_classes, conf_neg,
                                               blk_pos, blk_loc);
    topk_final_kernel<<<B_, 1024, 0, stream>>>(conf_neg, n_pos, blk_pos, blk_loc,
                                               hard, done, out);
}